// Round 3
// baseline (639.465 us; speedup 1.0000x reference)
//
#include <hip/hip_runtime.h>
#include <hip/hip_bf16.h>

typedef __attribute__((ext_vector_type(8))) short short8;
typedef __attribute__((ext_vector_type(4))) float f32x4;

#define N_NODES 16384
#define FEAT 128
#define NT 256   // K-tiles of 64 in spmm

__device__ __forceinline__ short f2bf(float x) {
  union { float f; unsigned u; } v;
  v.f = x;
  unsigned r = v.u + 0x7fffu + ((v.u >> 16) & 1u);  // RNE; inputs finite
  return (short)(r >> 16);
}

// ---------- Kernel 1: dinv[i] = rsqrt(1 + sum_j adj[i][j]) ----------
// Wave-per-row: no LDS, no __syncthreads, pure streaming + shfl reduce.
__global__ __launch_bounds__(256) void rowsum_kernel(
    const float* __restrict__ adj, float* __restrict__ dinv)
{
  const int w    = threadIdx.x >> 6;
  const int lane = threadIdx.x & 63;
  const int row  = (blockIdx.x << 2) + w;
  const float4* p4 = (const float4*)(adj + (size_t)row * N_NODES) + lane;
  float s = 0.f;
  #pragma unroll 8
  for (int it = 0; it < 64; ++it) {
    float4 v = p4[it << 6];
    s += (v.x + v.y) + (v.z + v.w);
  }
  #pragma unroll
  for (int off = 32; off > 0; off >>= 1) s += __shfl_down(s, off, 64);
  if (lane == 0) dinv[row] = rsqrtf(s + 1.0f);
}

// ---------- Kernel 2: Ypack[(k>>3)*1024 + f*8 + (k&7)] = bf16(d_k * (X@W)[k][f]) ----------
__global__ __launch_bounds__(256) void xw_kernel(
    const float* __restrict__ X, const float* __restrict__ W,
    const float* __restrict__ dinv,
    __hip_bfloat16* __restrict__ Ypack)
{
  __shared__ __align__(16) float Ws[64][128];
  __shared__ __align__(16) float Xs[32][128];
  __shared__ __align__(16) short Ts[128][40];
  const int tid = threadIdx.x;
  const int row0 = blockIdx.x << 5;

  {
    const float4* Xg = (const float4*)(X + ((size_t)row0 << 7));
    float4* Xl = (float4*)&Xs[0][0];
    #pragma unroll
    for (int i = 0; i < 4; ++i) Xl[tid + (i << 8)] = Xg[tid + (i << 8)];
  }
  const int f  = tid & 127;
  const int rr = tid >> 7;
  float acc[16];
  #pragma unroll
  for (int k = 0; k < 16; ++k) acc[k] = 0.f;

  for (int cc = 0; cc < 2; ++cc) {
    __syncthreads();
    {
      const float4* Wg = (const float4*)(W + ((size_t)cc << 13));
      float4* Wl = (float4*)&Ws[0][0];
      #pragma unroll
      for (int i = 0; i < 8; ++i) Wl[tid + (i << 8)] = Wg[tid + (i << 8)];
    }
    __syncthreads();
    for (int c4 = 0; c4 < 16; ++c4) {
      const int cl = c4 << 2;
      const float w0 = Ws[cl + 0][f];
      const float w1 = Ws[cl + 1][f];
      const float w2 = Ws[cl + 2][f];
      const float w3 = Ws[cl + 3][f];
      const int cg = (cc << 6) + cl;
      #pragma unroll
      for (int k = 0; k < 16; ++k) {
        const float4 x = *(const float4*)&Xs[rr + (k << 1)][cg];
        acc[k] += x.x * w0 + x.y * w1 + x.z * w2 + x.w * w3;
      }
    }
  }
  #pragma unroll
  for (int k = 0; k < 16; ++k) {
    const int r = rr + (k << 1);
    const float dv = dinv[row0 + r];
    Ts[f][r] = f2bf(acc[k] * dv);
  }
  __syncthreads();
  {
    const int f2 = tid >> 1;
    const int h  = (tid & 1) << 4;
    const short8 v0 = *(const short8*)&Ts[f2][h];
    const short8 v1 = *(const short8*)&Ts[f2][h + 8];
    short* o = (short*)Ypack;
    *(short8*)(o + (size_t)(row0 + h) * FEAT + (f2 << 3))     = v0;
    *(short8*)(o + (size_t)(row0 + h + 8) * FEAT + (f2 << 3)) = v1;
  }
}

// ---------- Kernel 3: out = relu(d_i * (A_hat @ Y)_i + b) ----------
// Barrier-free: A-frags AND B-frags loaded directly from global into regs,
// register ping-pong (1 iter ahead). Self-loop folded into A's diagonal.
#define SPMM_BODY(T, A0, A1, A2, A3, NA0, NA1, NA2, NA3, BC, BN)               \
  {                                                                            \
    if ((T) + 1 < NT) {                                                        \
      const float* ap = Ar + (((T) + 1) << 6);                                 \
      NA0 = *(const float4*)(ap);                                              \
      NA1 = *(const float4*)(ap + 4);                                          \
      NA2 = *(const float4*)(ap + 32);                                         \
      NA3 = *(const float4*)(ap + 36);                                         \
      const short* yp = Yg + (((T) + 1) << 13);                                \
      BN[0] = *(const short8*)(yp);                                            \
      BN[1] = *(const short8*)(yp + 128);                                      \
      BN[2] = *(const short8*)(yp + 256);                                      \
      BN[3] = *(const short8*)(yp + 384);                                      \
      BN[4] = *(const short8*)(yp + 4096);                                     \
      BN[5] = *(const short8*)(yp + 4224);                                     \
      BN[6] = *(const short8*)(yp + 4352);                                     \
      BN[7] = *(const short8*)(yp + 4480);                                     \
    }                                                                          \
    if ((T) == bid) {  /* self-loop: A_hat = A + I, uniform branch, 1/256 */   \
      A0.x += (dp0 == 0) ? 1.0f : 0.0f;  A0.y += (dp0 == 1) ? 1.0f : 0.0f;     \
      A0.z += (dp0 == 2) ? 1.0f : 0.0f;  A0.w += (dp0 == 3) ? 1.0f : 0.0f;     \
      A1.x += (dp0 == 4) ? 1.0f : 0.0f;  A1.y += (dp0 == 5) ? 1.0f : 0.0f;     \
      A1.z += (dp0 == 6) ? 1.0f : 0.0f;  A1.w += (dp0 == 7) ? 1.0f : 0.0f;     \
      A2.x += (dp1 == 0) ? 1.0f : 0.0f;  A2.y += (dp1 == 1) ? 1.0f : 0.0f;     \
      A2.z += (dp1 == 2) ? 1.0f : 0.0f;  A2.w += (dp1 == 3) ? 1.0f : 0.0f;     \
      A3.x += (dp1 == 4) ? 1.0f : 0.0f;  A3.y += (dp1 == 5) ? 1.0f : 0.0f;     \
      A3.z += (dp1 == 6) ? 1.0f : 0.0f;  A3.w += (dp1 == 7) ? 1.0f : 0.0f;     \
    }                                                                          \
    {                                                                          \
      short8 af0, af1;                                                         \
      af0[0] = f2bf(A0.x); af0[1] = f2bf(A0.y); af0[2] = f2bf(A0.z);           \
      af0[3] = f2bf(A0.w); af0[4] = f2bf(A1.x); af0[5] = f2bf(A1.y);           \
      af0[6] = f2bf(A1.z); af0[7] = f2bf(A1.w);                                \
      af1[0] = f2bf(A2.x); af1[1] = f2bf(A2.y); af1[2] = f2bf(A2.z);           \
      af1[3] = f2bf(A2.w); af1[4] = f2bf(A3.x); af1[5] = f2bf(A3.y);           \
      af1[6] = f2bf(A3.z); af1[7] = f2bf(A3.w);                                \
      acc[0] = __builtin_amdgcn_mfma_f32_16x16x32_bf16(af0, BC[0], acc[0], 0, 0, 0); \
      acc[1] = __builtin_amdgcn_mfma_f32_16x16x32_bf16(af0, BC[1], acc[1], 0, 0, 0); \
      acc[2] = __builtin_amdgcn_mfma_f32_16x16x32_bf16(af0, BC[2], acc[2], 0, 0, 0); \
      acc[3] = __builtin_amdgcn_mfma_f32_16x16x32_bf16(af0, BC[3], acc[3], 0, 0, 0); \
      acc[0] = __builtin_amdgcn_mfma_f32_16x16x32_bf16(af1, BC[4], acc[0], 0, 0, 0); \
      acc[1] = __builtin_amdgcn_mfma_f32_16x16x32_bf16(af1, BC[5], acc[1], 0, 0, 0); \
      acc[2] = __builtin_amdgcn_mfma_f32_16x16x32_bf16(af1, BC[6], acc[2], 0, 0, 0); \
      acc[3] = __builtin_amdgcn_mfma_f32_16x16x32_bf16(af1, BC[7], acc[3], 0, 0, 0); \
    }                                                                          \
  }

__global__ __launch_bounds__(512, 2) void spmm_kernel(
    const float* __restrict__ A,
    const __hip_bfloat16* __restrict__ Ypack,
    const float* __restrict__ dinv,
    const float* __restrict__ bias,
    float* __restrict__ out)
{
  const int tid  = threadIdx.x;
  const int bid  = blockIdx.x;
  const int row0 = bid << 6;

  const int wid  = tid >> 6;
  const int wm   = wid >> 1;        // 0..3: 16-row M-subtile
  const int wf   = wid & 1;         // 0..1: 64-col F-half
  const int lane = tid & 63;
  const int lm   = lane & 15;
  const int lk   = (lane >> 4) << 3;
  const int myrow = (wm << 4) + lm;           // 0..63 within block
  const int dp0 = myrow - lk;                 // diag hit in af0 if in [0,8)
  const int dp1 = myrow - 32 - lk;            // diag hit in af1 if in [0,8)

  const float* Ar = A + (size_t)(row0 + myrow) * N_NODES + lk;
  const short* Yg = (const short*)Ypack + (lk << 7) + (wf << 9) + (lm << 3);

  f32x4 acc[4];
  #pragma unroll
  for (int c = 0; c < 4; ++c) acc[c] = (f32x4){0.f, 0.f, 0.f, 0.f};

  float4 aA0, aA1, aA2, aA3, aB0, aB1, aB2, aB3;
  short8 b0[8], b1[8];

  // prologue: tile 0 -> cur regs
  aA0 = *(const float4*)(Ar);
  aA1 = *(const float4*)(Ar + 4);
  aA2 = *(const float4*)(Ar + 32);
  aA3 = *(const float4*)(Ar + 36);
  b0[0] = *(const short8*)(Yg);
  b0[1] = *(const short8*)(Yg + 128);
  b0[2] = *(const short8*)(Yg + 256);
  b0[3] = *(const short8*)(Yg + 384);
  b0[4] = *(const short8*)(Yg + 4096);
  b0[5] = *(const short8*)(Yg + 4224);
  b0[6] = *(const short8*)(Yg + 4352);
  b0[7] = *(const short8*)(Yg + 4480);

  for (int t = 0; t < NT; t += 2) {
    SPMM_BODY(t,     aA0, aA1, aA2, aA3, aB0, aB1, aB2, aB3, b0, b1)
    SPMM_BODY(t + 1, aB0, aB1, aB2, aB3, aA0, aA1, aA2, aA3, b1, b0)
  }

  // epilogue: out[row][col] = relu(d_row * acc + b[col])
  const int lr = (lane >> 4) << 2;
  float dreg[4];
  #pragma unroll
  for (int r = 0; r < 4; ++r) dreg[r] = dinv[row0 + (wm << 4) + lr + r];
  #pragma unroll
  for (int c = 0; c < 4; ++c) {
    const int col = (wf << 6) + (c << 4) + lm;
    const float bv = bias[col];
    #pragma unroll
    for (int r = 0; r < 4; ++r) {
      const int row = row0 + (wm << 4) + lr + r;
      const float v = dreg[r] * acc[c][r] + bv;
      out[(size_t)row * FEAT + col] = v > 0.f ? v : 0.f;
    }
  }
}

extern "C" void kernel_launch(void* const* d_in, const int* in_sizes, int n_in,
                              void* d_out, int out_size, void* d_ws, size_t ws_size,
                              hipStream_t stream) {
  const float* X   = (const float*)d_in[0];
  const float* adj = (const float*)d_in[1];
  const float* W   = (const float*)d_in[2];
  const float* b   = (const float*)d_in[3];
  float* out = (float*)d_out;

  float* dinv = (float*)d_ws;                                          // 64 KiB
  __hip_bfloat16* Ypack = (__hip_bfloat16*)((char*)d_ws + (1 << 16));  // 4 MiB

  rowsum_kernel<<<N_NODES / 4, 256, 0, stream>>>(adj, dinv);
  xw_kernel<<<N_NODES / 32, 256, 0, stream>>>(X, W, dinv, Ypack);
  spmm_kernel<<<N_NODES / 64, 512, 0, stream>>>(adj, Ypack, dinv, b, out);
}

// Round 4
// 409.625 us; speedup vs baseline: 1.5611x; 1.5611x over previous
//
#include <hip/hip_runtime.h>
#include <hip/hip_bf16.h>

typedef __attribute__((ext_vector_type(8))) short short8;
typedef __attribute__((ext_vector_type(4))) float f32x4;

#define N_NODES 16384
#define FEAT 128
#define NTILES 256          // K-tiles of 64 overall
#define KSPLIT 2
#define NT2 (NTILES / KSPLIT)

__device__ __forceinline__ short f2bf(float x) {
  union { float f; unsigned u; } v;
  v.f = x;
  unsigned r = v.u + 0x7fffu + ((v.u >> 16) & 1u);  // RNE; inputs finite
  return (short)(r >> 16);
}

// ---------- Kernel 1: dinv[i] = rsqrt(1 + sum_j adj[i][j]) ----------
__global__ __launch_bounds__(256) void rowsum_kernel(
    const float* __restrict__ adj, float* __restrict__ dinv)
{
  const int row = blockIdx.x;
  const float4* p4 = (const float4*)(adj + (size_t)row * N_NODES);
  float s = 0.f;
  #pragma unroll 4
  for (int i = threadIdx.x; i < N_NODES / 4; i += 256) {
    float4 v = p4[i];
    s += (v.x + v.y) + (v.z + v.w);
  }
  #pragma unroll
  for (int off = 32; off > 0; off >>= 1) s += __shfl_down(s, off, 64);
  __shared__ float part[4];
  if ((threadIdx.x & 63) == 0) part[threadIdx.x >> 6] = s;
  __syncthreads();
  if (threadIdx.x == 0) {
    float tot = (part[0] + part[1]) + (part[2] + part[3]) + 1.0f;
    dinv[row] = rsqrtf(tot);
  }
}

// ---------- Kernel 2: Ypack[(k>>3)*1024 + f*8 + (k&7)] = bf16(d_k * (X@W)[k][f]) ----------
__global__ __launch_bounds__(256) void xw_kernel(
    const float* __restrict__ X, const float* __restrict__ W,
    const float* __restrict__ dinv,
    __hip_bfloat16* __restrict__ Ypack)
{
  __shared__ __align__(16) float Ws[64][128];
  __shared__ __align__(16) float Xs[32][128];
  __shared__ __align__(16) short Ts[128][40];
  const int tid = threadIdx.x;
  const int row0 = blockIdx.x << 5;

  {
    const float4* Xg = (const float4*)(X + ((size_t)row0 << 7));
    float4* Xl = (float4*)&Xs[0][0];
    #pragma unroll
    for (int i = 0; i < 4; ++i) Xl[tid + (i << 8)] = Xg[tid + (i << 8)];
  }
  const int f  = tid & 127;
  const int rr = tid >> 7;
  float acc[16];
  #pragma unroll
  for (int k = 0; k < 16; ++k) acc[k] = 0.f;

  for (int cc = 0; cc < 2; ++cc) {
    __syncthreads();
    {
      const float4* Wg = (const float4*)(W + ((size_t)cc << 13));
      float4* Wl = (float4*)&Ws[0][0];
      #pragma unroll
      for (int i = 0; i < 8; ++i) Wl[tid + (i << 8)] = Wg[tid + (i << 8)];
    }
    __syncthreads();
    for (int c4 = 0; c4 < 16; ++c4) {
      const int cl = c4 << 2;
      const float w0 = Ws[cl + 0][f];
      const float w1 = Ws[cl + 1][f];
      const float w2 = Ws[cl + 2][f];
      const float w3 = Ws[cl + 3][f];
      const int cg = (cc << 6) + cl;
      #pragma unroll
      for (int k = 0; k < 16; ++k) {
        const float4 x = *(const float4*)&Xs[rr + (k << 1)][cg];
        acc[k] += x.x * w0 + x.y * w1 + x.z * w2 + x.w * w3;
      }
    }
  }
  #pragma unroll
  for (int k = 0; k < 16; ++k) {
    const int r = rr + (k << 1);
    const float dv = dinv[row0 + r];
    Ts[f][r] = f2bf(acc[k] * dv);
  }
  __syncthreads();
  {
    const int f2 = tid >> 1;
    const int h  = (tid & 1) << 4;
    const short8 v0 = *(const short8*)&Ts[f2][h];
    const short8 v1 = *(const short8*)&Ts[f2][h + 8];
    short* o = (short*)Ypack;
    *(short8*)(o + (size_t)(row0 + h) * FEAT + (f2 << 3))     = v0;
    *(short8*)(o + (size_t)(row0 + h + 8) * FEAT + (f2 << 3)) = v1;
  }
}

// ---------- Kernel 3: pws[s][row][f] = (A_hat[:, k-half s] @ Y-half)[row][f] ----------
// BM=64, BK=64, split-K=2 -> 512 blocks = 2 blocks/CU: one block's barrier
// drain overlaps the sibling's compute. Fragment-linear LDS (contiguous
// ds_read_b128 / ds_write_b128 everywhere). Self-loop folded into A diag.
__global__ __launch_bounds__(512, 4) void spmm_kernel(
    const float* __restrict__ A,
    const __hip_bfloat16* __restrict__ Ypack,
    float* __restrict__ pws)
{
  __shared__ __align__(16) short As[2][4096];   // [grp 0..7][row 0..63][j 0..7], 8 KiB/buf
  __shared__ __align__(16) short Bs[2][8192];   // [grp 0..7][f 0..127][j 0..7], 16 KiB/buf

  const int tid = threadIdx.x;
  const int bid = blockIdx.x;
  const int mt  = bid & 255;         // M-tile
  const int s   = bid >> 8;          // K-half
  const int row0 = mt << 6;

  // staging coords
  const int ar  = tid >> 3;          // A row 0..63
  const int akg = tid & 7;           // A k-group (8 floats)
  const float* Ag = A + (size_t)(row0 + ar) * N_NODES + (s * NT2 << 6) + (akg << 3);
  const short* Yg = (const short*)Ypack + ((size_t)(s * NT2) << 13) + (tid << 4);

  // compute coords
  const int wid  = tid >> 6;
  const int wm   = wid >> 1;
  const int wf   = wid & 1;
  const int lane = tid & 63;
  const int lm   = lane & 15;
  const int lkg  = (lane >> 4);      // 0..3 k-group within ks-half
  const int myrow = (wm << 4) + lm;

  f32x4 acc[4];
  #pragma unroll
  for (int c = 0; c < 4; ++c) acc[c] = (f32x4){0.f, 0.f, 0.f, 0.f};

  float4 a0, a1;
  short8 y0, y1;

#define LOADT(T)                                                               \
  {                                                                            \
    const float* ap = Ag + ((T) << 6);                                         \
    a0 = *(const float4*)(ap);                                                 \
    a1 = *(const float4*)(ap + 4);                                             \
    const short* yp = Yg + ((T) << 13);                                        \
    y0 = *(const short8*)(yp);                                                 \
    y1 = *(const short8*)(yp + 8);                                             \
  }

#define STORET(T, P)                                                           \
  {                                                                            \
    if (s * NT2 + (T) == mt && (ar >> 3) == akg) {  /* A_hat = A + I */        \
      const int j = ar & 7;                                                    \
      a0.x += (j == 0) ? 1.f : 0.f;  a0.y += (j == 1) ? 1.f : 0.f;             \
      a0.z += (j == 2) ? 1.f : 0.f;  a0.w += (j == 3) ? 1.f : 0.f;             \
      a1.x += (j == 4) ? 1.f : 0.f;  a1.y += (j == 5) ? 1.f : 0.f;             \
      a1.z += (j == 6) ? 1.f : 0.f;  a1.w += (j == 7) ? 1.f : 0.f;             \
    }                                                                          \
    short8 av;                                                                 \
    av[0] = f2bf(a0.x); av[1] = f2bf(a0.y); av[2] = f2bf(a0.z);                \
    av[3] = f2bf(a0.w); av[4] = f2bf(a1.x); av[5] = f2bf(a1.y);                \
    av[6] = f2bf(a1.z); av[7] = f2bf(a1.w);                                    \
    *(short8*)&As[P][(akg << 9) + (ar << 3)] = av;                             \
    *(short8*)&Bs[P][tid << 4]       = y0;                                     \
    *(short8*)&Bs[P][(tid << 4) + 8] = y1;                                     \
  }

#define COMP(P)                                                                \
  {                                                                            \
    const short8 af0 = *(const short8*)&As[P][(lkg << 9) + (myrow << 3)];      \
    acc[0] = __builtin_amdgcn_mfma_f32_16x16x32_bf16(af0,                      \
        *(const short8*)&Bs[P][(lkg << 10) + (((wf << 6) + lm) << 3)], acc[0], 0, 0, 0); \
    acc[1] = __builtin_amdgcn_mfma_f32_16x16x32_bf16(af0,                      \
        *(const short8*)&Bs[P][(lkg << 10) + (((wf << 6) + 16 + lm) << 3)], acc[1], 0, 0, 0); \
    acc[2] = __builtin_amdgcn_mfma_f32_16x16x32_bf16(af0,                      \
        *(const short8*)&Bs[P][(lkg << 10) + (((wf << 6) + 32 + lm) << 3)], acc[2], 0, 0, 0); \
    acc[3] = __builtin_amdgcn_mfma_f32_16x16x32_bf16(af0,                      \
        *(const short8*)&Bs[P][(lkg << 10) + (((wf << 6) + 48 + lm) << 3)], acc[3], 0, 0, 0); \
    const short8 af1 = *(const short8*)&As[P][((4 + lkg) << 9) + (myrow << 3)];\
    acc[0] = __builtin_amdgcn_mfma_f32_16x16x32_bf16(af1,                      \
        *(const short8*)&Bs[P][((4 + lkg) << 10) + (((wf << 6) + lm) << 3)], acc[0], 0, 0, 0); \
    acc[1] = __builtin_amdgcn_mfma_f32_16x16x32_bf16(af1,                      \
        *(const short8*)&Bs[P][((4 + lkg) << 10) + (((wf << 6) + 16 + lm) << 3)], acc[1], 0, 0, 0); \
    acc[2] = __builtin_amdgcn_mfma_f32_16x16x32_bf16(af1,                      \
        *(const short8*)&Bs[P][((4 + lkg) << 10) + (((wf << 6) + 32 + lm) << 3)], acc[2], 0, 0, 0); \
    acc[3] = __builtin_amdgcn_mfma_f32_16x16x32_bf16(af1,                      \
        *(const short8*)&Bs[P][((4 + lkg) << 10) + (((wf << 6) + 48 + lm) << 3)], acc[3], 0, 0, 0); \
  }

  // prologue
  LOADT(0)
  STORET(0, 0)
  __syncthreads();

  int p = 0;
  for (int t = 0; t < NT2; ++t) {
    if (t + 1 < NT2) LOADT(t + 1)        // issue early: latency hides under COMP
    COMP(p)
    if (t + 1 < NT2) STORET(t + 1, p ^ 1)
    __syncthreads();
    p ^= 1;
  }

  // write fp32 partial (no dinv/bias/relu here)
  float* pp = pws + ((size_t)(s * N_NODES + row0)) * FEAT;
  const int lr = (lane >> 4) << 2;
  #pragma unroll
  for (int c = 0; c < 4; ++c) {
    const int col = (wf << 6) + (c << 4) + lm;
    #pragma unroll
    for (int r = 0; r < 4; ++r) {
      pp[(size_t)((wm << 4) + lr + r) * FEAT + col] = acc[c][r];
    }
  }
#undef LOADT
#undef STORET
#undef COMP
}

// ---------- Kernel 4: out = relu(dinv[row] * (p0 + p1) + bias) ----------
__global__ __launch_bounds__(256) void reduce_kernel(
    const float* __restrict__ pws, const float* __restrict__ dinv,
    const float* __restrict__ bias, float* __restrict__ out)
{
  const int idx4 = blockIdx.x * 256 + threadIdx.x;     // 0..524287
  const int row  = idx4 >> 5;
  const int f4   = idx4 & 31;
  const float4 p0 = ((const float4*)pws)[idx4];
  const float4 p1 = ((const float4*)pws)[idx4 + (N_NODES * FEAT / 4)];
  const float4 bv = ((const float4*)bias)[f4];
  const float  d  = dinv[row];
  float4 v;
  v.x = d * (p0.x + p1.x) + bv.x;
  v.y = d * (p0.y + p1.y) + bv.y;
  v.z = d * (p0.z + p1.z) + bv.z;
  v.w = d * (p0.w + p1.w) + bv.w;
  v.x = v.x > 0.f ? v.x : 0.f;
  v.y = v.y > 0.f ? v.y : 0.f;
  v.z = v.z > 0.f ? v.z : 0.f;
  v.w = v.w > 0.f ? v.w : 0.f;
  ((float4*)out)[idx4] = v;
}

extern "C" void kernel_launch(void* const* d_in, const int* in_sizes, int n_in,
                              void* d_out, int out_size, void* d_ws, size_t ws_size,
                              hipStream_t stream) {
  const float* X   = (const float*)d_in[0];
  const float* adj = (const float*)d_in[1];
  const float* W   = (const float*)d_in[2];
  const float* b   = (const float*)d_in[3];
  float* out = (float*)d_out;

  float* dinv           = (float*)d_ws;                                   // 64 KiB
  __hip_bfloat16* Ypack = (__hip_bfloat16*)((char*)d_ws + (1 << 16));     // 4 MiB
  float* pws            = (float*)((char*)d_ws + (1 << 16) + (1 << 22));  // 16 MiB

  rowsum_kernel<<<N_NODES, 256, 0, stream>>>(adj, dinv);
  xw_kernel<<<N_NODES / 32, 256, 0, stream>>>(X, W, dinv, Ypack);
  spmm_kernel<<<NTILES * KSPLIT, 512, 0, stream>>>(adj, Ypack, pws);
  reduce_kernel<<<N_NODES * FEAT / 4 / 256, 256, 0, stream>>>(pws, dinv, b, out);
}

// Round 5
// 409.183 us; speedup vs baseline: 1.5628x; 1.0011x over previous
//
#include <hip/hip_runtime.h>
#include <hip/hip_bf16.h>

typedef __attribute__((ext_vector_type(8))) short short8;
typedef __attribute__((ext_vector_type(4))) float f32x4;

#define N_NODES 16384
#define FEAT 128
#define NTILES 256          // K-tiles of 64 overall
#define KSPLIT 2
#define NT2 (NTILES / KSPLIT)

__device__ __forceinline__ short f2bf(float x) {
  union { float f; unsigned u; } v;
  v.f = x;
  unsigned r = v.u + 0x7fffu + ((v.u >> 16) & 1u);  // RNE; inputs finite
  return (short)(r >> 16);
}

// ---------- Kernel 1: dinv[i] = rsqrt(1 + sum_j adj[i][j]) ----------
__global__ __launch_bounds__(256) void rowsum_kernel(
    const float* __restrict__ adj, float* __restrict__ dinv)
{
  const int row = blockIdx.x;
  const float4* p4 = (const float4*)(adj + (size_t)row * N_NODES);
  float s = 0.f;
  #pragma unroll 4
  for (int i = threadIdx.x; i < N_NODES / 4; i += 256) {
    float4 v = p4[i];
    s += (v.x + v.y) + (v.z + v.w);
  }
  #pragma unroll
  for (int off = 32; off > 0; off >>= 1) s += __shfl_down(s, off, 64);
  __shared__ float part[4];
  if ((threadIdx.x & 63) == 0) part[threadIdx.x >> 6] = s;
  __syncthreads();
  if (threadIdx.x == 0) {
    float tot = (part[0] + part[1]) + (part[2] + part[3]) + 1.0f;
    dinv[row] = rsqrtf(tot);
  }
}

// ---------- Kernel 2: Ypack[(k>>3)*1024 + f*8 + (k&7)] = bf16(d_k * (X@W)[k][f]) ----------
__global__ __launch_bounds__(256) void xw_kernel(
    const float* __restrict__ X, const float* __restrict__ W,
    const float* __restrict__ dinv,
    __hip_bfloat16* __restrict__ Ypack)
{
  __shared__ __align__(16) float Ws[64][128];
  __shared__ __align__(16) float Xs[32][128];
  __shared__ __align__(16) short Ts[128][40];
  const int tid = threadIdx.x;
  const int row0 = blockIdx.x << 5;

  {
    const float4* Xg = (const float4*)(X + ((size_t)row0 << 7));
    float4* Xl = (float4*)&Xs[0][0];
    #pragma unroll
    for (int i = 0; i < 4; ++i) Xl[tid + (i << 8)] = Xg[tid + (i << 8)];
  }
  const int f  = tid & 127;
  const int rr = tid >> 7;
  float acc[16];
  #pragma unroll
  for (int k = 0; k < 16; ++k) acc[k] = 0.f;

  for (int cc = 0; cc < 2; ++cc) {
    __syncthreads();
    {
      const float4* Wg = (const float4*)(W + ((size_t)cc << 13));
      float4* Wl = (float4*)&Ws[0][0];
      #pragma unroll
      for (int i = 0; i < 8; ++i) Wl[tid + (i << 8)] = Wg[tid + (i << 8)];
    }
    __syncthreads();
    for (int c4 = 0; c4 < 16; ++c4) {
      const int cl = c4 << 2;
      const float w0 = Ws[cl + 0][f];
      const float w1 = Ws[cl + 1][f];
      const float w2 = Ws[cl + 2][f];
      const float w3 = Ws[cl + 3][f];
      const int cg = (cc << 6) + cl;
      #pragma unroll
      for (int k = 0; k < 16; ++k) {
        const float4 x = *(const float4*)&Xs[rr + (k << 1)][cg];
        acc[k] += x.x * w0 + x.y * w1 + x.z * w2 + x.w * w3;
      }
    }
  }
  #pragma unroll
  for (int k = 0; k < 16; ++k) {
    const int r = rr + (k << 1);
    const float dv = dinv[row0 + r];
    Ts[f][r] = f2bf(acc[k] * dv);
  }
  __syncthreads();
  {
    const int f2 = tid >> 1;
    const int h  = (tid & 1) << 4;
    const short8 v0 = *(const short8*)&Ts[f2][h];
    const short8 v1 = *(const short8*)&Ts[f2][h + 8];
    short* o = (short*)Ypack;
    *(short8*)(o + (size_t)(row0 + h) * FEAT + (f2 << 3))     = v0;
    *(short8*)(o + (size_t)(row0 + h + 8) * FEAT + (f2 << 3)) = v1;
  }
}

// ---------- Kernel 3: pws[s][row][f] = (A_hat[:, k-half s] @ Y-half)[row][f] ----------
// split-K=2 (2 blocks/CU). Raw s_barrier + counted vmcnt (no vmcnt(0) drain),
// 2-deep register prefetch (load t+2 while storing t+1), setprio around MFMA.
__global__ __launch_bounds__(512, 4) void spmm_kernel(
    const float* __restrict__ A,
    const __hip_bfloat16* __restrict__ Ypack,
    float* __restrict__ pws)
{
  __shared__ __align__(16) short As[2][4096];   // [kgrp][row][8], 8 KiB/buf
  __shared__ __align__(16) short Bs[2][8192];   // [kgrp][f][8], 16 KiB/buf

  const int tid = threadIdx.x;
  const int bid = blockIdx.x;
  const int mt  = bid & 255;         // M-tile
  const int s   = bid >> 8;          // K-half
  const int row0 = mt << 6;

  const int ar  = tid >> 3;          // A row 0..63
  const int akg = tid & 7;           // A k-group (8 floats)
  const float* Ag = A + (size_t)(row0 + ar) * N_NODES + (s * NT2 << 6) + (akg << 3);
  const short* Yg = (const short*)Ypack + ((size_t)(s * NT2) << 13) + (tid << 4);

  const int wid  = tid >> 6;
  const int wm   = wid >> 1;
  const int wf   = wid & 1;
  const int lane = tid & 63;
  const int lm   = lane & 15;
  const int lkg  = (lane >> 4);
  const int myrow = (wm << 4) + lm;

  f32x4 acc[4];
  #pragma unroll
  for (int c = 0; c < 4; ++c) acc[c] = (f32x4){0.f, 0.f, 0.f, 0.f};

  float4 a0A, a1A, a0B, a1B;
  short8 y0A, y1A, y0B, y1B;

#define LOADT(T, A0_, A1_, Y0_, Y1_)                                           \
  {                                                                            \
    const float* ap = Ag + ((size_t)(T) << 6);                                 \
    A0_ = *(const float4*)(ap);                                                \
    A1_ = *(const float4*)(ap + 4);                                            \
    const short* yp = Yg + ((size_t)(T) << 13);                                \
    Y0_ = *(const short8*)(yp);                                                \
    Y1_ = *(const short8*)(yp + 8);                                            \
  }

#define STORET(T, P, A0_, A1_, Y0_, Y1_)                                       \
  {                                                                            \
    if (s * NT2 + (T) == mt && (ar >> 3) == akg) {  /* A_hat = A + I */        \
      const int j = ar & 7;                                                    \
      A0_.x += (j == 0) ? 1.f : 0.f;  A0_.y += (j == 1) ? 1.f : 0.f;           \
      A0_.z += (j == 2) ? 1.f : 0.f;  A0_.w += (j == 3) ? 1.f : 0.f;           \
      A1_.x += (j == 4) ? 1.f : 0.f;  A1_.y += (j == 5) ? 1.f : 0.f;           \
      A1_.z += (j == 6) ? 1.f : 0.f;  A1_.w += (j == 7) ? 1.f : 0.f;           \
    }                                                                          \
    short8 av;                                                                 \
    av[0] = f2bf(A0_.x); av[1] = f2bf(A0_.y); av[2] = f2bf(A0_.z);             \
    av[3] = f2bf(A0_.w); av[4] = f2bf(A1_.x); av[5] = f2bf(A1_.y);             \
    av[6] = f2bf(A1_.z); av[7] = f2bf(A1_.w);                                  \
    *(short8*)&As[P][(akg << 9) + (ar << 3)] = av;                             \
    *(short8*)&Bs[P][tid << 4]       = Y0_;                                    \
    *(short8*)&Bs[P][(tid << 4) + 8] = Y1_;                                    \
  }

#define COMP(P)                                                                \
  {                                                                            \
    const short8 af0 = *(const short8*)&As[P][(lkg << 9) + (myrow << 3)];      \
    acc[0] = __builtin_amdgcn_mfma_f32_16x16x32_bf16(af0,                      \
        *(const short8*)&Bs[P][(lkg << 10) + (((wf << 6) + lm) << 3)], acc[0], 0, 0, 0); \
    acc[1] = __builtin_amdgcn_mfma_f32_16x16x32_bf16(af0,                      \
        *(const short8*)&Bs[P][(lkg << 10) + (((wf << 6) + 16 + lm) << 3)], acc[1], 0, 0, 0); \
    acc[2] = __builtin_amdgcn_mfma_f32_16x16x32_bf16(af0,                      \
        *(const short8*)&Bs[P][(lkg << 10) + (((wf << 6) + 32 + lm) << 3)], acc[2], 0, 0, 0); \
    acc[3] = __builtin_amdgcn_mfma_f32_16x16x32_bf16(af0,                      \
        *(const short8*)&Bs[P][(lkg << 10) + (((wf << 6) + 48 + lm) << 3)], acc[3], 0, 0, 0); \
    const short8 af1 = *(const short8*)&As[P][((4 + lkg) << 9) + (myrow << 3)];\
    acc[0] = __builtin_amdgcn_mfma_f32_16x16x32_bf16(af1,                      \
        *(const short8*)&Bs[P][((4 + lkg) << 10) + (((wf << 6) + lm) << 3)], acc[0], 0, 0, 0); \
    acc[1] = __builtin_amdgcn_mfma_f32_16x16x32_bf16(af1,                      \
        *(const short8*)&Bs[P][((4 + lkg) << 10) + (((wf << 6) + 16 + lm) << 3)], acc[1], 0, 0, 0); \
    acc[2] = __builtin_amdgcn_mfma_f32_16x16x32_bf16(af1,                      \
        *(const short8*)&Bs[P][((4 + lkg) << 10) + (((wf << 6) + 32 + lm) << 3)], acc[2], 0, 0, 0); \
    acc[3] = __builtin_amdgcn_mfma_f32_16x16x32_bf16(af1,                      \
        *(const short8*)&Bs[P][((4 + lkg) << 10) + (((wf << 6) + 48 + lm) << 3)], acc[3], 0, 0, 0); \
  }

#define BAR()                                                                  \
  asm volatile("s_waitcnt lgkmcnt(0)" ::: "memory");                           \
  __builtin_amdgcn_s_barrier();

  // prologue: tiles 0,1 -> regs; stage tile 0
  LOADT(0, a0A, a1A, y0A, y1A)
  LOADT(1, a0B, a1B, y0B, y1B)
  STORET(0, 0, a0A, a1A, y0A, y1A)   // compiler waits only tile-0 loads (counted)
  BAR()

  for (int t = 0; t < NT2; t += 2) {
    // iter t: compute buf0, stage t+1 (regs B, loaded a full iter ago), load t+2
    if (t + 2 < NT2) LOADT(t + 2, a0A, a1A, y0A, y1A)
    __builtin_amdgcn_s_setprio(1);
    COMP(0)
    __builtin_amdgcn_s_setprio(0);
    if (t + 1 < NT2) STORET(t + 1, 1, a0B, a1B, y0B, y1B)
    BAR()
    // iter t+1: compute buf1, stage t+2 (regs A), load t+3
    if (t + 3 < NT2) LOADT(t + 3, a0B, a1B, y0B, y1B)
    __builtin_amdgcn_s_setprio(1);
    COMP(1)
    __builtin_amdgcn_s_setprio(0);
    if (t + 2 < NT2) STORET(t + 2, 0, a0A, a1A, y0A, y1A)
    BAR()
  }

  // write fp32 partial
  float* pp = pws + ((size_t)(s * N_NODES + row0)) * FEAT;
  const int lr = (lane >> 4) << 2;
  #pragma unroll
  for (int c = 0; c < 4; ++c) {
    const int col = (wf << 6) + (c << 4) + lm;
    #pragma unroll
    for (int r = 0; r < 4; ++r) {
      pp[(size_t)((wm << 4) + lr + r) * FEAT + col] = acc[c][r];
    }
  }
#undef LOADT
#undef STORET
#undef COMP
#undef BAR
}

// ---------- Kernel 4: out = relu(dinv[row] * (p0 + p1) + bias) ----------
__global__ __launch_bounds__(256) void reduce_kernel(
    const float* __restrict__ pws, const float* __restrict__ dinv,
    const float* __restrict__ bias, float* __restrict__ out)
{
  const int idx4 = blockIdx.x * 256 + threadIdx.x;
  const int row  = idx4 >> 5;
  const int f4   = idx4 & 31;
  const float4 p0 = ((const float4*)pws)[idx4];
  const float4 p1 = ((const float4*)pws)[idx4 + (N_NODES * FEAT / 4)];
  const float4 bv = ((const float4*)bias)[f4];
  const float  d  = dinv[row];
  float4 v;
  v.x = d * (p0.x + p1.x) + bv.x;
  v.y = d * (p0.y + p1.y) + bv.y;
  v.z = d * (p0.z + p1.z) + bv.z;
  v.w = d * (p0.w + p1.w) + bv.w;
  v.x = v.x > 0.f ? v.x : 0.f;
  v.y = v.y > 0.f ? v.y : 0.f;
  v.z = v.z > 0.f ? v.z : 0.f;
  v.w = v.w > 0.f ? v.w : 0.f;
  ((float4*)out)[idx4] = v;
}

extern "C" void kernel_launch(void* const* d_in, const int* in_sizes, int n_in,
                              void* d_out, int out_size, void* d_ws, size_t ws_size,
                              hipStream_t stream) {
  const float* X   = (const float*)d_in[0];
  const float* adj = (const float*)d_in[1];
  const float* W   = (const float*)d_in[2];
  const float* b   = (const float*)d_in[3];
  float* out = (float*)d_out;

  float* dinv           = (float*)d_ws;                                   // 64 KiB
  __hip_bfloat16* Ypack = (__hip_bfloat16*)((char*)d_ws + (1 << 16));     // 4 MiB
  float* pws            = (float*)((char*)d_ws + (1 << 16) + (1 << 22));  // 16 MiB

  rowsum_kernel<<<N_NODES, 256, 0, stream>>>(adj, dinv);
  xw_kernel<<<N_NODES / 32, 256, 0, stream>>>(X, W, dinv, Ypack);
  spmm_kernel<<<NTILES * KSPLIT, 512, 0, stream>>>(adj, Ypack, pws);
  reduce_kernel<<<N_NODES * FEAT / 4 / 256, 256, 0, stream>>>(pws, dinv, b, out);
}